// Round 2
// baseline (951.934 us; speedup 1.0000x reference)
//
#include <hip/hip_runtime.h>
#include <hip/hip_bf16.h>
#include <math.h>

// ---------------------------------------------------------------------------
// Expansion kernel: out[b,80,80] from per-sample generated tensor-product
// weights.  Q-form fusion: out[b,uv] = sum_{c,w} h[b,c]*x[b,w]*lw2[c,n(w,uv)]
// -> per-sample A-vector Q[b, w*64+c] (bf16, register-resident) x fixed
// B-matrix (transposed lw2, bf16) via mfma_f32_16x16x32_bf16.
// Round 2: g split 2->4 (grid 1024, 4 blocks/CU), XCD-affine blockIdx layout
// (XCD = g + 4*(btile&1)) so each XCD's L2 holds only its 1.15 MB B-slice.
// ---------------------------------------------------------------------------

typedef short bf16x8 __attribute__((ext_vector_type(8)));
typedef float f32x4 __attribute__((ext_vector_type(4)));

static __device__ __forceinline__ short f2bf(float f) {
  unsigned u = __builtin_bit_cast(unsigned, f);
  u = u + 0x7fffu + ((u >> 16) & 1u);   // round-to-nearest-even
  return (short)(u >> 16);
}

// ---- pre-pass 1: LW2 [64][36864] f32 -> LW2T bf16 [36864][64] ------------
__global__ void k_transpose(const float* __restrict__ lw2, short* __restrict__ lw2t) {
  __shared__ float tile[64][65];
  int n0 = blockIdx.x * 64;
  int t = threadIdx.x;
#pragma unroll
  for (int k = 0; k < 16; ++k) {
    int idx = k * 256 + t;
    int c = idx >> 6, j = idx & 63;
    tile[c][j] = lw2[(size_t)c * 36864 + n0 + j];
  }
  __syncthreads();
#pragma unroll
  for (int k = 0; k < 16; ++k) {
    int idx = k * 256 + t;
    int n = idx >> 6, c = idx & 63;
    lw2t[(size_t)(n0 + n) * 64 + c] = f2bf(tile[c][n]);
  }
}

// ---- pre-pass 2: packed bias matrices ------------------------------------
__global__ void k_bias(const float* __restrict__ bw2, const float* __restrict__ lb2,
                       const float* __restrict__ bb2,
                       short* __restrict__ bb00, short* __restrict__ bb11,
                       short* __restrict__ bb01, short* __restrict__ bb10) {
  int r = blockIdx.x * 256 + threadIdx.x;
  if (r < 1024) {
    int uv = r;
    for (int k = 0; k < 64; ++k) bb00[uv * 96 + k] = f2bf(bw2[k * 1280 + uv]);
    for (int w = 0; w < 16; ++w) bb00[uv * 96 + 64 + w] = f2bf(lb2[w * 1024 + uv]);
    bb00[uv * 96 + 80] = f2bf(bb2[uv]);
    for (int k = 81; k < 96; ++k) bb00[uv * 96 + k] = 0;
  } else if (r < 1280) {
    int uv = r - 1024;
    for (int k = 0; k < 64; ++k) bb11[uv * 96 + k] = f2bf(bw2[k * 1280 + 1024 + uv]);
    for (int w = 0; w < 16; ++w) bb11[uv * 96 + 64 + w] = f2bf(lb2[16384 + w * 256 + uv]);
    bb11[uv * 96 + 80] = f2bf(bb2[1024 + uv]);
    for (int k = 81; k < 96; ++k) bb11[uv * 96 + k] = 0;
  } else if (r < 1792) {
    int uv = r - 1280;
    for (int w = 0; w < 16; ++w) bb01[uv * 32 + w] = f2bf(lb2[20480 + w * 512 + uv]);
    for (int k = 16; k < 32; ++k) bb01[uv * 32 + k] = 0;
  } else if (r < 2304) {
    int uv = r - 1792;
    for (int w = 0; w < 16; ++w) bb10[uv * 32 + w] = f2bf(lb2[28672 + w * 512 + uv]);
    for (int k = 16; k < 32; ++k) bb10[uv * 32 + k] = 0;
  }
}

// ---- pre-pass 3: per-sample h, h2, x0, x1 --------------------------------
__global__ void k_samples(const float* __restrict__ feat, const float* __restrict__ ne,
                          const float* __restrict__ W0, const float* __restrict__ W1,
                          const float* __restrict__ lw1, const float* __restrict__ lb1,
                          const float* __restrict__ bw1, const float* __restrict__ bb1,
                          float* __restrict__ H, float* __restrict__ H2,
                          float* __restrict__ X0, float* __restrict__ X1) {
  int b = blockIdx.x;
  int t = threadIdx.x;               // 192 threads
  __shared__ float sne[128];
  __shared__ float sf[320];
  if (t < 128) sne[t] = ne[(size_t)b * 128 + t];
  for (int i = t; i < 320; i += 192) sf[i] = feat[(size_t)b * 320 + i];
  __syncthreads();
  if (t < 64) {
    float a = lb1[t];
    for (int k = 0; k < 128; ++k) a += sne[k] * lw1[k * 64 + t];
    H[(size_t)b * 64 + t] = a / (1.0f + expf(-a));
  } else if (t < 128) {
    int c = t - 64;
    float a = bb1[c];
    for (int k = 0; k < 128; ++k) a += sne[k] * bw1[k * 64 + c];
    H2[(size_t)b * 64 + c] = a / (1.0f + expf(-a));
  } else if (t < 144) {
    int v = t - 128;
    float a = 0.0f;
    for (int u = 0; u < 128; ++u) a += sf[u] * W0[u * 16 + v];
    X0[(size_t)b * 16 + v] = a * 0.08838834764831845f;  // 1/sqrt(128)
  } else {
    int idx = t - 144, v = idx / 3, j = idx % 3;        // idx < 48
    float a = 0.0f;
    for (int u = 0; u < 64; ++u) a += sf[128 + u * 3 + j] * W1[u * 16 + v];
    X1[(size_t)b * 48 + v * 3 + j] = a * 0.125f;        // 1/sqrt(64)
  }
}

// ---- main kernel ----------------------------------------------------------
template <int NOFF, int NSTR, int NBIAS, int BBW>
static __device__ __forceinline__ void mm_pair(
    const short* __restrict__ LW2T, const short* __restrict__ BB,
    const bf16x8 (&A)[32], const bf16x8* __restrict__ Ab,
    int uv0, int uv1, int col, int q, f32x4& acc0, f32x4& acc1) {
#pragma unroll
  for (int kk = 0; kk < 32; ++kk) {
    int base = kk * 32 + q * 8;
    int w = base >> 6, c0 = base & 63;
    const bf16x8 B0 = *(const bf16x8*)(LW2T + (size_t)(NOFF + w * NSTR + uv0 + col) * 64 + c0);
    const bf16x8 B1 = *(const bf16x8*)(LW2T + (size_t)(NOFF + w * NSTR + uv1 + col) * 64 + c0);
    acc0 = __builtin_amdgcn_mfma_f32_16x16x32_bf16(A[kk], B0, acc0, 0, 0, 0);
    acc1 = __builtin_amdgcn_mfma_f32_16x16x32_bf16(A[kk], B1, acc1, 0, 0, 0);
  }
#pragma unroll
  for (int kk = 0; kk < NBIAS; ++kk) {
    int base = kk * 32 + q * 8;
    const bf16x8 B0 = *(const bf16x8*)(BB + (uv0 + col) * BBW + base);
    const bf16x8 B1 = *(const bf16x8*)(BB + (uv1 + col) * BBW + base);
    acc0 = __builtin_amdgcn_mfma_f32_16x16x32_bf16(Ab[kk], B0, acc0, 0, 0, 0);
    acc1 = __builtin_amdgcn_mfma_f32_16x16x32_bf16(Ab[kk], B1, acc1, 0, 0, 0);
  }
}

template <int NOFF, int NSTR, int NBIAS, int BBW>
static __device__ __forceinline__ void mm_single(
    const short* __restrict__ LW2T, const short* __restrict__ BB,
    const bf16x8 (&A)[32], const bf16x8* __restrict__ Ab,
    int uv0, int col, int q, f32x4& acc0) {
#pragma unroll
  for (int kk = 0; kk < 32; ++kk) {
    int base = kk * 32 + q * 8;
    int w = base >> 6, c0 = base & 63;
    const bf16x8 B0 = *(const bf16x8*)(LW2T + (size_t)(NOFF + w * NSTR + uv0 + col) * 64 + c0);
    acc0 = __builtin_amdgcn_mfma_f32_16x16x32_bf16(A[kk], B0, acc0, 0, 0, 0);
  }
#pragma unroll
  for (int kk = 0; kk < NBIAS; ++kk) {
    int base = kk * 32 + q * 8;
    const bf16x8 B0 = *(const bf16x8*)(BB + (uv0 + col) * BBW + base);
    acc0 = __builtin_amdgcn_mfma_f32_16x16x32_bf16(Ab[kk], B0, acc0, 0, 0, 0);
  }
}

__global__ __launch_bounds__(256, 4) void k_main(
    const short* __restrict__ LW2T,
    const short* __restrict__ BB00, const short* __restrict__ BB11,
    const short* __restrict__ BB01, const short* __restrict__ BB10,
    const float* __restrict__ H, const float* __restrict__ H2,
    const float* __restrict__ X0, const float* __restrict__ X1,
    float* __restrict__ out) {
  constexpr float S00 = 0.0625f;                  // 1/16
  constexpr float S3 = 0.036084391824351614f;     // (1/sqrt(3))/16

  // blockIdx = btile*4 + g  ->  XCD = blockIdx%8 = g + 4*(btile&1):
  // each XCD's L2 only ever sees one g-slice of LW2T (~1.15 MB < 4 MiB).
  int wg = blockIdx.x;
  int btile = wg >> 2, g = wg & 3;
  int b0 = btile << 4;
  int t = threadIdx.x;
  int lane = t & 63, wave = t >> 6;
  int col = lane & 15, q = lane >> 4;

  __shared__ float sH[16][68];
  __shared__ float sH2[16][68];
  __shared__ float sX0[16][17];
  __shared__ float sX1[16][51];

  for (int i = t; i < 1024; i += 256) {
    int b = i >> 6, c = i & 63;
    sH[b][c]  = H[(size_t)(b0 + b) * 64 + c];
    sH2[b][c] = H2[(size_t)(b0 + b) * 64 + c];
  }
  sX0[t >> 4][t & 15] = X0[(size_t)(b0 + (t >> 4)) * 16 + (t & 15)];
  for (int i = t; i < 768; i += 256)
    sX1[i / 48][i % 48] = X1[(size_t)(b0 + i / 48) * 48 + (i % 48)];
  __syncthreads();

  bf16x8 A[32];
  bf16x8 Ab[3];

  // =============== Phase A: Q0 = h * x0  (paths 00, 11) ===================
#pragma unroll
  for (int kk = 0; kk < 32; ++kk) {
    int base = kk * 32 + q * 8;
    int w = base >> 6, c0 = base & 63;
    float xw = sX0[col][w];
    bf16x8 a;
#pragma unroll
    for (int e = 0; e < 8; ++e) a[e] = f2bf(sH[col][c0 + e] * xw);
    A[kk] = a;
  }
#pragma unroll
  for (int kk = 0; kk < 3; ++kk) {
    bf16x8 a;
#pragma unroll
    for (int e = 0; e < 8; ++e) {
      int k = kk * 32 + q * 8 + e;
      float v = 0.0f;
      if (k < 64) v = sH2[col][k];
      else if (k < 80) v = sX0[col][k - 64];
      else if (k == 80) v = 1.0f;
      a[e] = f2bf(v);
    }
    Ab[kk] = a;
  }

  // path00: uv = u*32+v < 1024, n = w*1024+uv, out (u, v), scale 1/16
#pragma unroll 1
  for (int pp = 0; pp < 2; ++pp) {
    int uv0 = (g * 16 + wave * 4 + pp * 2) * 16;
    int uv1 = uv0 + 16;
    f32x4 acc0 = {0.f, 0.f, 0.f, 0.f}, acc1 = {0.f, 0.f, 0.f, 0.f};
    mm_pair<0, 1024, 3, 96>(LW2T, BB00, A, Ab, uv0, uv1, col, q, acc0, acc1);
#pragma unroll
    for (int i = 0; i < 4; ++i) {
      size_t ob = (size_t)(b0 + q * 4 + i) * 6400;
      int uA = uv0 + col, uB = uv1 + col;
      out[ob + (uA >> 5) * 80 + (uA & 31)] = acc0[i] * S00;
      out[ob + (uB >> 5) * 80 + (uB & 31)] = acc1[i] * S00;
    }
  }

  // path11: uv = u*16+v < 256, n = 16384+w*256+uv, out 3x3 diag blocks
  {
    int uv0 = (g * 4 + wave) * 16;
    f32x4 acc0 = {0.f, 0.f, 0.f, 0.f};
    mm_single<16384, 256, 3, 96>(LW2T, BB11, A, Ab, uv0, col, q, acc0);
#pragma unroll
    for (int i = 0; i < 4; ++i) {
      size_t ob = (size_t)(b0 + q * 4 + i) * 6400;
      int uv = uv0 + col;
      float val = acc0[i] * S3;
      int u = uv >> 4, v = uv & 15;
      float* p = out + ob + (size_t)(32 + 3 * u) * 80 + (32 + 3 * v);
      p[0] = val;   p[1] = 0.f;   p[2] = 0.f;
      p[80] = 0.f;  p[81] = val;  p[82] = 0.f;
      p[160] = 0.f; p[161] = 0.f; p[162] = val;
    }
  }

  // =============== Phase B: Q1j = h * x1[:, :, j]  (paths 01, 10) =========
#pragma unroll 1
  for (int j = 0; j < 3; ++j) {
#pragma unroll
    for (int kk = 0; kk < 32; ++kk) {
      int base = kk * 32 + q * 8;
      int w = base >> 6, c0 = base & 63;
      float xw = sX1[col][w * 3 + j];
      bf16x8 a;
#pragma unroll
      for (int e = 0; e < 8; ++e) a[e] = f2bf(sH[col][c0 + e] * xw);
      A[kk] = a;
    }
    bf16x8 A1;
#pragma unroll
    for (int e = 0; e < 8; ++e) {
      int k = q * 8 + e;
      A1[e] = (k < 16) ? f2bf(sX1[col][k * 3 + j]) : (short)0;
    }

    // path01: uv = u*16+v < 512, n = 20480+w*512+uv, out (u, 32+3v+j)
    {
      int uv0 = (g * 8 + wave * 2) * 16;
      int uv1 = uv0 + 16;
      f32x4 acc0 = {0.f, 0.f, 0.f, 0.f}, acc1 = {0.f, 0.f, 0.f, 0.f};
      mm_pair<20480, 512, 1, 32>(LW2T, BB01, A, &A1, uv0, uv1, col, q, acc0, acc1);
#pragma unroll
      for (int i = 0; i < 4; ++i) {
        size_t ob = (size_t)(b0 + q * 4 + i) * 6400;
        int uA = uv0 + col, uB = uv1 + col;
        out[ob + (uA >> 4) * 80 + 32 + 3 * (uA & 15) + j] = acc0[i] * S3;
        out[ob + (uB >> 4) * 80 + 32 + 3 * (uB & 15) + j] = acc1[i] * S3;
      }
    }
    // path10: uv = u*32+v < 512, n = 28672+w*512+uv, out (32+3u+j, v)
    {
      int uv0 = (g * 8 + wave * 2) * 16;
      int uv1 = uv0 + 16;
      f32x4 acc0 = {0.f, 0.f, 0.f, 0.f}, acc1 = {0.f, 0.f, 0.f, 0.f};
      mm_pair<28672, 512, 1, 32>(LW2T, BB10, A, &A1, uv0, uv1, col, q, acc0, acc1);
#pragma unroll
      for (int i = 0; i < 4; ++i) {
        size_t ob = (size_t)(b0 + q * 4 + i) * 6400;
        int uA = uv0 + col, uB = uv1 + col;
        out[ob + (size_t)(32 + 3 * (uA >> 5) + j) * 80 + (uA & 31)] = acc0[i] * S3;
        out[ob + (size_t)(32 + 3 * (uB >> 5) + j) * 80 + (uB & 31)] = acc1[i] * S3;
      }
    }
  }
}

// ---------------------------------------------------------------------------
extern "C" void kernel_launch(void* const* d_in, const int* in_sizes, int n_in,
                              void* d_out, int out_size, void* d_ws, size_t ws_size,
                              hipStream_t stream) {
  const float* feat = (const float*)d_in[0];
  const float* ne   = (const float*)d_in[1];
  const float* W0   = (const float*)d_in[2];
  const float* W1   = (const float*)d_in[3];
  const float* lw1  = (const float*)d_in[4];
  const float* lb1  = (const float*)d_in[5];
  const float* lw2  = (const float*)d_in[6];
  const float* lb2  = (const float*)d_in[7];
  const float* bw1  = (const float*)d_in[8];
  const float* bb1  = (const float*)d_in[9];
  const float* bw2  = (const float*)d_in[10];
  const float* bb2  = (const float*)d_in[11];

  char* ws = (char*)d_ws;
  short* LW2T = (short*)ws; ws += (size_t)36864 * 64 * 2;   // 4.72 MB
  short* BB00 = (short*)ws; ws += (size_t)1024 * 96 * 2;
  short* BB11 = (short*)ws; ws += (size_t)256 * 96 * 2;
  short* BB01 = (short*)ws; ws += (size_t)512 * 32 * 2;
  short* BB10 = (short*)ws; ws += (size_t)512 * 32 * 2;
  float* H  = (float*)ws;   ws += (size_t)4096 * 64 * 4;
  float* H2 = (float*)ws;   ws += (size_t)4096 * 64 * 4;
  float* X0 = (float*)ws;   ws += (size_t)4096 * 16 * 4;
  float* X1 = (float*)ws;   ws += (size_t)4096 * 48 * 4;
  (void)ws_size; (void)in_sizes; (void)n_in; (void)out_size;

  hipLaunchKernelGGL(k_transpose, dim3(576), dim3(256), 0, stream, lw2, LW2T);
  hipLaunchKernelGGL(k_bias, dim3(9), dim3(256), 0, stream, bw2, lb2, bb2,
                     BB00, BB11, BB01, BB10);
  hipLaunchKernelGGL(k_samples, dim3(4096), dim3(192), 0, stream,
                     feat, ne, W0, W1, lw1, lb1, bw1, bb1, H, H2, X0, X1);
  hipLaunchKernelGGL(k_main, dim3(1024), dim3(256), 0, stream,
                     LW2T, BB00, BB11, BB01, BB10, H, H2, X0, X1, (float*)d_out);
}

// Round 3
// 614.019 us; speedup vs baseline: 1.5503x; 1.5503x over previous
//
#include <hip/hip_runtime.h>
#include <hip/hip_bf16.h>
#include <math.h>

// ---------------------------------------------------------------------------
// Expansion kernel.  Q-form fusion: out[b,uv] = sum_k Q[b,k]*LW2T[n(uv),k]
// Round 3: Q (A-operand) lives in LDS, built cooperatively per block and
// shared by all 4 waves -> frees VGPRs so the unrolled kk loop can pipeline
// the global B loads (round 1 was a serial dependent-load chain; round 2's
// launch_bounds(256,4) spilled A to scratch: FETCH 1.1 GB).
// ---------------------------------------------------------------------------

typedef short bf16x8 __attribute__((ext_vector_type(8)));
typedef float f32x4 __attribute__((ext_vector_type(4)));

static __device__ __forceinline__ short f2bf(float f) {
  unsigned u = __builtin_bit_cast(unsigned, f);
  u = u + 0x7fffu + ((u >> 16) & 1u);   // round-to-nearest-even
  return (short)(u >> 16);
}

// ---- pre-pass 1: LW2 [64][36864] f32 -> LW2T bf16 [36864][64] ------------
__global__ void k_transpose(const float* __restrict__ lw2, short* __restrict__ lw2t) {
  __shared__ float tile[64][65];
  int n0 = blockIdx.x * 64;
  int t = threadIdx.x;
#pragma unroll
  for (int k = 0; k < 16; ++k) {
    int idx = k * 256 + t;
    int c = idx >> 6, j = idx & 63;
    tile[c][j] = lw2[(size_t)c * 36864 + n0 + j];
  }
  __syncthreads();
#pragma unroll
  for (int k = 0; k < 16; ++k) {
    int idx = k * 256 + t;
    int n = idx >> 6, c = idx & 63;
    lw2t[(size_t)(n0 + n) * 64 + c] = f2bf(tile[c][n]);
  }
}

// ---- pre-pass 2: packed bias matrices ------------------------------------
__global__ void k_bias(const float* __restrict__ bw2, const float* __restrict__ lb2,
                       const float* __restrict__ bb2,
                       short* __restrict__ bb00, short* __restrict__ bb11,
                       short* __restrict__ bb01, short* __restrict__ bb10) {
  int r = blockIdx.x * 256 + threadIdx.x;
  if (r < 1024) {
    int uv = r;
    for (int k = 0; k < 64; ++k) bb00[uv * 96 + k] = f2bf(bw2[k * 1280 + uv]);
    for (int w = 0; w < 16; ++w) bb00[uv * 96 + 64 + w] = f2bf(lb2[w * 1024 + uv]);
    bb00[uv * 96 + 80] = f2bf(bb2[uv]);
    for (int k = 81; k < 96; ++k) bb00[uv * 96 + k] = 0;
  } else if (r < 1280) {
    int uv = r - 1024;
    for (int k = 0; k < 64; ++k) bb11[uv * 96 + k] = f2bf(bw2[k * 1280 + 1024 + uv]);
    for (int w = 0; w < 16; ++w) bb11[uv * 96 + 64 + w] = f2bf(lb2[16384 + w * 256 + uv]);
    bb11[uv * 96 + 80] = f2bf(bb2[1024 + uv]);
    for (int k = 81; k < 96; ++k) bb11[uv * 96 + k] = 0;
  } else if (r < 1792) {
    int uv = r - 1280;
    for (int w = 0; w < 16; ++w) bb01[uv * 32 + w] = f2bf(lb2[20480 + w * 512 + uv]);
    for (int k = 16; k < 32; ++k) bb01[uv * 32 + k] = 0;
  } else if (r < 2304) {
    int uv = r - 1792;
    for (int w = 0; w < 16; ++w) bb10[uv * 32 + w] = f2bf(lb2[28672 + w * 512 + uv]);
    for (int k = 16; k < 32; ++k) bb10[uv * 32 + k] = 0;
  }
}

// ---- pre-pass 3: per-sample h, h2, x0, x1 --------------------------------
__global__ void k_samples(const float* __restrict__ feat, const float* __restrict__ ne,
                          const float* __restrict__ W0, const float* __restrict__ W1,
                          const float* __restrict__ lw1, const float* __restrict__ lb1,
                          const float* __restrict__ bw1, const float* __restrict__ bb1,
                          float* __restrict__ H, float* __restrict__ H2,
                          float* __restrict__ X0, float* __restrict__ X1) {
  int b = blockIdx.x;
  int t = threadIdx.x;               // 192 threads
  __shared__ float sne[128];
  __shared__ float sf[320];
  if (t < 128) sne[t] = ne[(size_t)b * 128 + t];
  for (int i = t; i < 320; i += 192) sf[i] = feat[(size_t)b * 320 + i];
  __syncthreads();
  if (t < 64) {
    float a = lb1[t];
    for (int k = 0; k < 128; ++k) a += sne[k] * lw1[k * 64 + t];
    H[(size_t)b * 64 + t] = a / (1.0f + expf(-a));
  } else if (t < 128) {
    int c = t - 64;
    float a = bb1[c];
    for (int k = 0; k < 128; ++k) a += sne[k] * bw1[k * 64 + c];
    H2[(size_t)b * 64 + c] = a / (1.0f + expf(-a));
  } else if (t < 144) {
    int v = t - 128;
    float a = 0.0f;
    for (int u = 0; u < 128; ++u) a += sf[u] * W0[u * 16 + v];
    X0[(size_t)b * 16 + v] = a * 0.08838834764831845f;  // 1/sqrt(128)
  } else {
    int idx = t - 144, v = idx / 3, j = idx % 3;        // idx < 48
    float a = 0.0f;
    for (int u = 0; u < 64; ++u) a += sf[128 + u * 3 + j] * W1[u * 16 + v];
    X1[(size_t)b * 48 + v * 3 + j] = a * 0.125f;        // 1/sqrt(64)
  }
}

// ---- main kernel ----------------------------------------------------------
// A (Q matrix) in LDS, shared across waves.  B streamed from global (L2).
template <int N, int NOFF, int NSTR, int NBIAS, int BBW>
static __device__ __forceinline__ void mm_frags(
    const short* __restrict__ LW2T, const short* __restrict__ BB,
    const short (&sQv)[4][32][16][8], const short* __restrict__ Abq,
    int uvbase, int col, int q, f32x4 (&acc)[N]) {
#pragma unroll
  for (int kk = 0; kk < 32; ++kk) {
    const bf16x8 A = *(const bf16x8*)&sQv[q][kk][col][0];
    int base = kk * 32 + q * 8;
    int w = base >> 6, c0 = base & 63;
    const short* brow = LW2T + (size_t)(NOFF + w * NSTR + uvbase + col) * 64 + c0;
#pragma unroll
    for (int i = 0; i < N; ++i) {
      const bf16x8 B = *(const bf16x8*)(brow + i * (16 * 64));
      acc[i] = __builtin_amdgcn_mfma_f32_16x16x32_bf16(A, B, acc[i], 0, 0, 0);
    }
  }
#pragma unroll
  for (int kk = 0; kk < NBIAS; ++kk) {
    const bf16x8 A = *(const bf16x8*)(Abq + kk * 128);
    int base = kk * 32 + q * 8;
#pragma unroll
    for (int i = 0; i < N; ++i) {
      const bf16x8 B = *(const bf16x8*)(BB + (uvbase + i * 16 + col) * BBW + base);
      acc[i] = __builtin_amdgcn_mfma_f32_16x16x32_bf16(A, B, acc[i], 0, 0, 0);
    }
  }
}

__global__ __launch_bounds__(256, 3) void k_main(
    const short* __restrict__ LW2T,
    const short* __restrict__ BB00, const short* __restrict__ BB11,
    const short* __restrict__ BB01, const short* __restrict__ BB10,
    const float* __restrict__ H, const float* __restrict__ H2,
    const float* __restrict__ X0, const float* __restrict__ X1,
    float* __restrict__ out) {
  constexpr float S00 = 0.0625f;                  // 1/16
  constexpr float S3 = 0.036084391824351614f;     // (1/sqrt(3))/16

  // blockIdx = btile*4 + g  ->  XCD = g + 4*(btile&1): each XCD's L2 only
  // sees one g-slice of LW2T (~1.18 MB < 4 MiB).
  int wg = blockIdx.x;
  int btile = wg >> 2, g = wg & 3;
  int b0 = btile << 4;
  int t = threadIdx.x;
  int lane = t & 63, wave = t >> 6;
  int col = lane & 15, q = lane >> 4;

  __shared__ float sH[16][68];
  __shared__ float sH2[16][68];
  __shared__ float sX0[16][17];
  __shared__ float sX1[16][51];
  __shared__ short sQ[4][32][16][8];   // Q[k = kk*32+q*8+e] for sample col
  __shared__ short sAb[4][3][16][8];   // bias A-fragments (phase A)
  __shared__ short sA1[4][16][8];      // bias A-fragment (phase B)

  for (int i = t; i < 1024; i += 256) {
    int b = i >> 6, c = i & 63;
    sH[b][c]  = H[(size_t)(b0 + b) * 64 + c];
    sH2[b][c] = H2[(size_t)(b0 + b) * 64 + c];
  }
  sX0[t >> 4][t & 15] = X0[(size_t)(b0 + (t >> 4)) * 16 + (t & 15)];
  for (int i = t; i < 768; i += 256)
    sX1[i / 48][i % 48] = X1[(size_t)(b0 + i / 48) * 48 + (i % 48)];
  __syncthreads();

  // =============== Phase A: Q0 = h * x0  (paths 00, 11) ===================
  // cooperative build: 8192 bf16-pairs
  for (int i = t; i < 8192; i += 256) {
    int qq = i >> 11, kk = (i >> 6) & 31, cc = (i >> 2) & 15, e2 = (i & 3) << 1;
    int k = kk * 32 + qq * 8 + e2;
    int w = k >> 6, c = k & 63;
    float xw = sX0[cc][w];
    unsigned lo = (unsigned short)f2bf(sH[cc][c] * xw);
    unsigned hi = (unsigned short)f2bf(sH[cc][c + 1] * xw);
    *(unsigned*)&sQ[qq][kk][cc][e2] = lo | (hi << 16);
  }
  for (int i = t; i < 1536; i += 256) {
    int qq = i / 384, rem = i - qq * 384;
    int kk = rem >> 7, cc = (rem >> 3) & 15, e = rem & 7;
    int k = kk * 32 + qq * 8 + e;
    float v = 0.0f;
    if (k < 64) v = sH2[cc][k];
    else if (k < 80) v = sX0[cc][k - 64];
    else if (k == 80) v = 1.0f;
    sAb[qq][kk][cc][e] = f2bf(v);
  }
  __syncthreads();

  // path00: uv = u*32+v < 1024, out (u, v), scale 1/16
  {
    int uvbase = (g * 16 + wave * 4) * 16;
    f32x4 acc[4] = {};
    mm_frags<4, 0, 1024, 3, 96>(LW2T, BB00, sQ, &sAb[q][0][col][0],
                                uvbase, col, q, acc);
#pragma unroll
    for (int i = 0; i < 4; ++i)
#pragma unroll
      for (int ii = 0; ii < 4; ++ii) {
        size_t ob = (size_t)(b0 + q * 4 + ii) * 6400;
        int uv = uvbase + i * 16 + col;
        out[ob + (uv >> 5) * 80 + (uv & 31)] = acc[i][ii] * S00;
      }
  }

  // path11: uv = u*16+v < 256, out 3x3 diag blocks
  {
    int uvbase = (g * 4 + wave) * 16;
    f32x4 acc[1] = {};
    mm_frags<1, 16384, 256, 3, 96>(LW2T, BB11, sQ, &sAb[q][0][col][0],
                                   uvbase, col, q, acc);
#pragma unroll
    for (int ii = 0; ii < 4; ++ii) {
      size_t ob = (size_t)(b0 + q * 4 + ii) * 6400;
      int uv = uvbase + col;
      float val = acc[0][ii] * S3;
      int u = uv >> 4, v = uv & 15;
      float* p = out + ob + (size_t)(32 + 3 * u) * 80 + (32 + 3 * v);
      p[0] = val;   p[1] = 0.f;   p[2] = 0.f;
      p[80] = 0.f;  p[81] = val;  p[82] = 0.f;
      p[160] = 0.f; p[161] = 0.f; p[162] = val;
    }
  }

  // =============== Phase B: Q1j = h * x1[:,:,j]  (paths 01, 10) ===========
#pragma unroll 1
  for (int j = 0; j < 3; ++j) {
    __syncthreads();   // all waves done reading sQ
    for (int i = t; i < 8192; i += 256) {
      int qq = i >> 11, kk = (i >> 6) & 31, cc = (i >> 2) & 15, e2 = (i & 3) << 1;
      int k = kk * 32 + qq * 8 + e2;
      int w = k >> 6, c = k & 63;
      float xw = sX1[cc][w * 3 + j];
      unsigned lo = (unsigned short)f2bf(sH[cc][c] * xw);
      unsigned hi = (unsigned short)f2bf(sH[cc][c + 1] * xw);
      *(unsigned*)&sQ[qq][kk][cc][e2] = lo | (hi << 16);
    }
    for (int i = t; i < 512; i += 256) {
      int qq = i >> 7, cc = (i >> 3) & 15, e = i & 7;
      int k = qq * 8 + e;
      sA1[qq][cc][e] = (k < 16) ? f2bf(sX1[cc][k * 3 + j]) : (short)0;
    }
    __syncthreads();

    // path01: uv = u*16+v < 512, out (u, 32+3v+j)
    {
      int uvbase = (g * 8 + wave * 2) * 16;
      f32x4 acc[2] = {};
      mm_frags<2, 20480, 512, 1, 32>(LW2T, BB01, sQ, &sA1[q][col][0],
                                     uvbase, col, q, acc);
#pragma unroll
      for (int i = 0; i < 2; ++i)
#pragma unroll
        for (int ii = 0; ii < 4; ++ii) {
          size_t ob = (size_t)(b0 + q * 4 + ii) * 6400;
          int uv = uvbase + i * 16 + col;
          out[ob + (uv >> 4) * 80 + 32 + 3 * (uv & 15) + j] = acc[i][ii] * S3;
        }
    }
    // path10: uv = u*32+v < 512, out (32+3u+j, v)
    {
      int uvbase = (g * 8 + wave * 2) * 16;
      f32x4 acc[2] = {};
      mm_frags<2, 28672, 512, 1, 32>(LW2T, BB10, sQ, &sA1[q][col][0],
                                     uvbase, col, q, acc);
#pragma unroll
      for (int i = 0; i < 2; ++i)
#pragma unroll
        for (int ii = 0; ii < 4; ++ii) {
          size_t ob = (size_t)(b0 + q * 4 + ii) * 6400;
          int uv = uvbase + i * 16 + col;
          out[ob + (size_t)(32 + 3 * (uv >> 5) + j) * 80 + (uv & 31)] = acc[i][ii] * S3;
        }
    }
  }
}

// ---------------------------------------------------------------------------
extern "C" void kernel_launch(void* const* d_in, const int* in_sizes, int n_in,
                              void* d_out, int out_size, void* d_ws, size_t ws_size,
                              hipStream_t stream) {
  const float* feat = (const float*)d_in[0];
  const float* ne   = (const float*)d_in[1];
  const float* W0   = (const float*)d_in[2];
  const float* W1   = (const float*)d_in[3];
  const float* lw1  = (const float*)d_in[4];
  const float* lb1  = (const float*)d_in[5];
  const float* lw2  = (const float*)d_in[6];
  const float* lb2  = (const float*)d_in[7];
  const float* bw1  = (const float*)d_in[8];
  const float* bb1  = (const float*)d_in[9];
  const float* bw2  = (const float*)d_in[10];
  const float* bb2  = (const float*)d_in[11];

  char* ws = (char*)d_ws;
  short* LW2T = (short*)ws; ws += (size_t)36864 * 64 * 2;   // 4.72 MB
  short* BB00 = (short*)ws; ws += (size_t)1024 * 96 * 2;
  short* BB11 = (short*)ws; ws += (size_t)256 * 96 * 2;
  short* BB01 = (short*)ws; ws += (size_t)512 * 32 * 2;
  short* BB10 = (short*)ws; ws += (size_t)512 * 32 * 2;
  float* H  = (float*)ws;   ws += (size_t)4096 * 64 * 4;
  float* H2 = (float*)ws;   ws += (size_t)4096 * 64 * 4;
  float* X0 = (float*)ws;   ws += (size_t)4096 * 16 * 4;
  float* X1 = (float*)ws;   ws += (size_t)4096 * 48 * 4;
  (void)ws_size; (void)in_sizes; (void)n_in; (void)out_size;

  hipLaunchKernelGGL(k_transpose, dim3(576), dim3(256), 0, stream, lw2, LW2T);
  hipLaunchKernelGGL(k_bias, dim3(9), dim3(256), 0, stream, bw2, lb2, bb2,
                     BB00, BB11, BB01, BB10);
  hipLaunchKernelGGL(k_samples, dim3(4096), dim3(192), 0, stream,
                     feat, ne, W0, W1, lw1, lb1, bw1, bb1, H, H2, X0, X1);
  hipLaunchKernelGGL(k_main, dim3(1024), dim3(256), 0, stream,
                     LW2T, BB00, BB11, BB01, BB10, H, H2, X0, X1, (float*)d_out);
}